// Round 12
// baseline (42.603 us; speedup 1.0000x reference)
//
#include <hip/hip_runtime.h>
#include <math.h>

typedef _Float16 f16x8 __attribute__((ext_vector_type(8)));
typedef float f32x4 __attribute__((ext_vector_type(4)));

// ---------------------------------------------------------------------------
// qry (256c,16384px) f32; sup_x (5,256,128,128) f32; sup_y (5,128,128) f32.
// M=1280 protos, C=256. out (16384) f32.
// pred[px] = sum_m softmax(mask? d : NEG)_m * d_m, d = 20*<q_n[px], p_n[m]>.
// Identity: sum_c q_n[c] = 0 => <q_n,(x-mu)*inv> = inv*<q_n,x> => MFMA on RAW
// pooled x (f16); epilogue d = alpha[m]*acc, alpha = 20/max(||x-mu||,1e-4)
// from deterministic per-block partial sums. d<=20 -> fixed-max softmax:
// e = mk*exp(d-20); masked -> exactly 0.
// pro_raw PRE-SWIZZLED: row m, 16B chunk g stored at g ^ (m&7) -> linear
// global_load_lds staging + conflict-free ds_read_b128 at ch = (ks*4+lq)^ln7.
// R9 lesson: cooperative grid.sync ~90us on MI355X -- keep separate kernels.
// R12: pool = 1280 blocks (5/CU balance; R11's 640 = 2.5/CU tail) with fully
// contiguous 4KB issues (one channel-slab per iteration).
// ---------------------------------------------------------------------------

// K1: blocks 0..1279 = (s, gy, cq): pool 16 channels x 16 cells (gy grid-row)
//     -> pro_raw chunks (swizzled f16) + psum[m][32] partials.
//     Blocks 1280..1284: pool sup_y shot r -> yv_ws.
__global__ __launch_bounds__(256) void pool_kernel(const float* __restrict__ sup_x,
                                                   const float* __restrict__ sup_y,
                                                   _Float16* __restrict__ pro_raw,
                                                   float* __restrict__ psum,
                                                   float* __restrict__ yv_ws) {
    const int b = blockIdx.x, t = threadIdx.x;
    if (b < 1280) {
        __shared__ float hs[16 * 264];      // 16.9 KB: per-channel h-4sums, padded
        __shared__ float xa[16][17];        // [gx][c] pooled values
        const int s = b >> 8, rem = b & 255;
        const int gy = rem >> 4, cq = rem & 15;
        const float* base = sup_x + ((size_t)(s * 256 + cq * 16) * 128 + gy * 8) * 128;
#pragma unroll
        for (int it = 0; it < 16; ++it) {   // one channel slab = 4KB contiguous
            const float4 v = *(const float4*)(base + (size_t)it * 16384 + t * 4);
            hs[it * 264 + t] = v.x + v.y + v.z + v.w;
        }
        __syncthreads();
        {   // vertical 8-row sum: t -> (c = t>>4, gx = t&15)
            const int c = t >> 4, gx = t & 15;
            float sum = 0.f;
#pragma unroll
            for (int r = 0; r < 8; ++r)
                sum += hs[c * 264 + r * 32 + gx * 2] + hs[c * 264 + r * 32 + gx * 2 + 1];
            xa[gx][c] = sum * (1.f / 64.f);
        }
        __syncthreads();
        if (t < 32) {                        // 16 m x 2 chunks f16, swizzled
            const int gx = t >> 1, j = t & 1;
            const int m = s * 256 + gy * 16 + gx;
            const int g = cq * 2 + j;
            f16x8 hv;
#pragma unroll
            for (int jj = 0; jj < 8; ++jj) hv[jj] = (_Float16)xa[gx][j * 8 + jj];
            *(f16x8*)(pro_raw + (size_t)m * 256 + ((g ^ (m & 7)) << 3)) = hv;
        } else if (t < 48) {                 // partial stats over this block's 16 c
            const int gx = t - 32;
            float s1 = 0.f, s2 = 0.f;
#pragma unroll
            for (int c = 0; c < 16; ++c) { const float x = xa[gx][c]; s1 += x; s2 += x * x; }
            const int m = s * 256 + gy * 16 + gx;
            psum[m * 32 + cq * 2]     = s1;
            psum[m * 32 + cq * 2 + 1] = s2;
        }
    } else {
        const int r = b - 1280;
        const int gy = t >> 4, gx = t & 15;
        const float* base = sup_y + r * 16384 + gy * 1024 + gx * 8;
        float sum = 0.f;
#pragma unroll
        for (int rr = 0; rr < 8; ++rr) {
            const float4 a = *(const float4*)(base + rr * 128);
            const float4 bb = *(const float4*)(base + rr * 128 + 4);
            sum += a.x + a.y + a.z + a.w + bb.x + bb.y + bb.z + bb.w;
        }
        yv_ws[r * 256 + t] = sum * (1.f / 64.f);
    }
}

__device__ __forceinline__ void gload_lds16h(const _Float16* g, _Float16* l) {
    __builtin_amdgcn_global_load_lds((const __attribute__((address_space(1))) unsigned int*)g,
                                     (__attribute__((address_space(3))) unsigned int*)l,
                                     16, 0, 0);
}
__device__ __forceinline__ void gload_lds16f(const float* g, float* l) {
    __builtin_amdgcn_global_load_lds((const __attribute__((address_space(1))) unsigned int*)g,
                                     (__attribute__((address_space(3))) unsigned int*)l,
                                     16, 0, 0);
}

// stage one 128m x 256c f16 tile: wave w stages ITS OWN 16 rows (8KB slice)
__device__ __forceinline__ void stage_tile(const _Float16* __restrict__ pro_raw,
                                           int tile, _Float16* dst, int w, int l) {
#pragma unroll
    for (int i = 0; i < 8; ++i) {
        const int off = w * 4096 + i * 512 + l * 8;
        gload_lds16h(pro_raw + (size_t)tile * 32768 + off, dst + off);
    }
}

// compute one 128-m tile: wave owns rows w*16..w*16+15.
// epilogue: d = alpha[m]*acc ; e = mk*exp(d-20) ; S += e ; W += e*d
__device__ __forceinline__ void compute_tile(const _Float16* __restrict__ pb,
                                             const float* __restrict__ msp,
                                             const float* __restrict__ asp,
                                             const f16x8 (&bfr)[4][8],
                                             int row, int ln7, int lq,
                                             float (&Sa)[4], float (&Wa)[4]) {
    f32x4 acc[4];
#pragma unroll
    for (int p = 0; p < 4; ++p) acc[p] = (f32x4){0.f, 0.f, 0.f, 0.f};
#pragma unroll
    for (int ks = 0; ks < 8; ++ks) {
        const int ch = (ks * 4 + lq) ^ ln7;          // bank-correct swizzle
        const f16x8 a = *(const f16x8*)(pb + row * 256 + ch * 8);
#pragma unroll
        for (int p = 0; p < 4; ++p)
            acc[p] = __builtin_amdgcn_mfma_f32_16x16x32_f16(a, bfr[p][ks], acc[p], 0, 0, 0);
    }
    const f32x4 mkv = *(const f32x4*)(msp + lq * 4);
    const f32x4 av  = *(const f32x4*)(asp + lq * 4);
#pragma unroll
    for (int p = 0; p < 4; ++p) {
        float ssum = 0.f, wsum = 0.f;
#pragma unroll
        for (int r = 0; r < 4; ++r) {
            const float d = av[r] * acc[p][r];
            const float e = mkv[r] * __expf(d - 20.f);
            ssum += e; wsum += e * d;
        }
        Sa[p] += ssum; Wa[p] += wsum;
    }
}

// K2: 256 blocks x 512 thr. Prologue: stage qry -> qtf (async), meanwhile
// reduce psum -> alpha[m] + masks from yv_ws; qnorm -> qs f16; hoist B-frags.
// Main: 10 tiles of 128 m, per-wave dbuf + counted vmcnt (R10 pipeline).
__global__ __launch_bounds__(512, 2) void main_kernel(const float* __restrict__ qry,
                                                      const _Float16* __restrict__ pro_raw,
                                                      const float* __restrict__ psum,
                                                      const float* __restrict__ yv_ws,
                                                      float* __restrict__ out) {
    __shared__ __align__(16) _Float16 arena[65536];   // 128 KB
    __shared__ float ms[1280];
    __shared__ float alf[1280];
    __shared__ float scr[1024];
    __shared__ float2 stats[64];
    __shared__ int iflags[2];

    float*     qtf  = (float*)arena;        // 64 KB [c][64px] (prologue)
    _Float16*  qs   = arena + 32768;        // bytes [64K,96K) (prologue)
    _Float16*  buf0 = arena;                // bytes [0,64K)   (main)
    _Float16*  buf1 = arena + 32768;        // bytes [64K,128K)(main)
    float*     red  = (float*)arena;        // 16 KB (epilogue, overlays buf0)

    const int t = threadIdx.x;
    const int w = t >> 6, l = t & 63;
    const int ln = l & 15, lq = l >> 4;
    const int ln7 = ln & 7;
    const int px0 = blockIdx.x * 64;

    if (t < 2) iflags[t] = 0;
    __syncthreads();

    // ---- issue qry staging (latency hidden by alpha/mask compute below) ----
#pragma unroll
    for (int i = 0; i < 8; ++i) {
        const int c = i * 32 + (t >> 4);
        gload_lds16f(qry + (size_t)c * 16384 + px0 + (t & 15) * 4,
                     qtf + i * 2048 + t * 4);
    }

    // ---- alpha[m] from psum partials + mask flags (m = t, t+512, t+1024) ----
    float yv3[3];
    int f0 = 0, f1 = 0;
#pragma unroll
    for (int k = 0; k < 3; ++k) {
        const int m = t + k * 512;
        if (m < 1280) {
            float S1 = 0.f, S2 = 0.f;
            const f32x4* pp = (const f32x4*)(psum + m * 32);
#pragma unroll
            for (int u = 0; u < 8; ++u) {
                const f32x4 p = pp[u];
                S1 += p[0] + p[2]; S2 += p[1] + p[3];
            }
            alf[m] = 20.f / fmaxf(sqrtf(fmaxf(S2 - S1 * S1 * (1.f / 256.f), 0.f)), 1e-4f);
            const float y = yv_ws[m];
            yv3[k] = y;
            if (y > 0.5f) f0 = 1;
            if (y > 0.1f) f1 = 1;
        }
    }
    if (f0) atomicOr(&iflags[0], 1);
    if (f1) atomicOr(&iflags[1], 1);
    __syncthreads();   // full drain: qtf ready, flags final
    {
        const int mode = iflags[0] ? 0 : (iflags[1] ? 1 : 2);
#pragma unroll
        for (int k = 0; k < 3; ++k) {
            const int m = t + k * 512;
            if (m < 1280)
                ms[m] = (mode == 0) ? (yv3[k] > 0.5f ? 1.f : 0.f)
                      : (mode == 1) ? (yv3[k] > 0.1f ? 1.f : 0.f) : 1.f;
        }
    }

    // ---- qnorm: per-px stats then f16 convert into qs (swizzled) ----
    {
        const int p = t & 63, q = t >> 6;
        float s1 = 0.f, s2 = 0.f;
        for (int cc = 0; cc < 32; ++cc) {
            const float x = qtf[(q * 32 + cc) * 64 + p];
            s1 += x; s2 += x * x;
        }
        scr[q * 64 + p] = s1; scr[512 + q * 64 + p] = s2;
    }
    __syncthreads();
    if (t < 64) {
        float S1 = 0.f, S2 = 0.f;
        for (int q = 0; q < 8; ++q) { S1 += scr[q * 64 + t]; S2 += scr[512 + q * 64 + t]; }
        const float mu = S1 * (1.f / 256.f);
        const float nrm = sqrtf(fmaxf(S2 - 256.f * mu * mu, 0.f));
        stats[t] = make_float2(mu, 1.f / fmaxf(nrm, 1e-4f));
    }
    __syncthreads();
    {
        const int px = t & 63, e = t >> 6;
        const float2 st = stats[px];
#pragma unroll
        for (int u = 0; u < 4; ++u) {
            const int g = e * 4 + u;
            f16x8 hv;
#pragma unroll
            for (int j = 0; j < 8; ++j)
                hv[j] = (_Float16)((qtf[(g * 8 + j) * 64 + px] - st.x) * st.y);
            *(f16x8*)(qs + px * 256 + ((g ^ (px & 7)) << 3)) = hv;
        }
    }
    __syncthreads();   // qs ready; qtf dead -> buf0 region free

    stage_tile(pro_raw, 0, buf0, w, l);   // overlaps bfr hoist

    f16x8 bfr[4][8];
#pragma unroll
    for (int p = 0; p < 4; ++p) {
        const int px = p * 16 + ln;
        const int sB = px & 7;
#pragma unroll
        for (int ks = 0; ks < 8; ++ks) {
            const int g = ks * 4 + lq;
            bfr[p][ks] = *(const f16x8*)(qs + px * 256 + ((g ^ sB) << 3));
        }
    }
    __syncthreads();   // all waves done reading qs -> buf1 region free

    stage_tile(pro_raw, 1, buf1, w, l);

    const int row = w * 16 + ln;
    float Sa[4] = {0.f, 0.f, 0.f, 0.f}, Wa[4] = {0.f, 0.f, 0.f, 0.f};

#pragma unroll 1
    for (int tile = 0; tile < 10; ++tile) {
        if (tile < 8) asm volatile("s_waitcnt vmcnt(8)" ::: "memory");
        else          asm volatile("s_waitcnt vmcnt(0)" ::: "memory");
        compute_tile((tile & 1) ? buf1 : buf0,
                     ms + tile * 128 + w * 16, alf + tile * 128 + w * 16,
                     bfr, row, ln7, lq, Sa, Wa);
        if (tile < 8) {
            asm volatile("s_waitcnt lgkmcnt(0)" ::: "memory");
            __builtin_amdgcn_sched_barrier(0);
            stage_tile(pro_raw, tile + 2, (tile & 1) ? buf1 : buf0, w, l);
        }
    }

    __syncthreads();   // all waves done with buffers -> red overlay safe
#pragma unroll
    for (int p = 0; p < 4; ++p) {
        const int px = p * 16 + ln;
        const int slot = (w * 4 + lq + px) & 31;
        red[px * 32 + slot] = Sa[p];
        red[2048 + px * 32 + slot] = Wa[p];
    }
    __syncthreads();
    if (t < 64) {
        float S = 0.f, W = 0.f;
        for (int s = 0; s < 32; ++s) {
            const int slot = (s + t) & 31;
            S += red[t * 32 + slot];
            W += red[2048 + t * 32 + slot];
        }
        out[px0 + t] = W / S;
    }
}

extern "C" void kernel_launch(void* const* d_in, const int* in_sizes, int n_in,
                              void* d_out, int out_size, void* d_ws, size_t ws_size,
                              hipStream_t stream) {
    const float* qry   = (const float*)d_in[0];   // 256*16384
    const float* sup_x = (const float*)d_in[1];   // 5*256*16384
    const float* sup_y = (const float*)d_in[2];   // 5*16384
    float* out = (float*)d_out;                   // 16384

    char* ws = (char*)d_ws;
    _Float16*  pro_raw = (_Float16*)ws;           ws += 1280 * 256 * 2;   // 640 KB
    float*     psum    = (float*)ws;              ws += 1280 * 32 * 4;    // 160 KB
    float*     yv_ws   = (float*)ws;              /* 5 KB */

    pool_kernel<<<1285, 256, 0, stream>>>(sup_x, sup_y, pro_raw, psum, yv_ws);
    main_kernel<<<256, 512, 0, stream>>>(qry, pro_raw, psum, yv_ws, out);
}

// Round 13
// 42.585 us; speedup vs baseline: 1.0004x; 1.0004x over previous
//
#include <hip/hip_runtime.h>
#include <math.h>

typedef _Float16 f16x8 __attribute__((ext_vector_type(8)));
typedef float f32x4 __attribute__((ext_vector_type(4)));

// ---------------------------------------------------------------------------
// qry (256c,16384px) f32; sup_x (5,256,128,128) f32; sup_y (5,128,128) f32.
// M=1280 protos, C=256. out (16384) f32.
// pred[px] = sum_m softmax(mask? d : NEG)_m * d_m, d = 20*<q_n[px], p_n[m]>.
// Identity: sum_c q_n[c] = 0 => <q_n,(x-mu)*inv> = inv*<q_n,x> => MFMA on RAW
// pooled x (f16); epilogue d = alpha[m]*acc, alpha = 20/max(||x-mu||,1e-4)
// from deterministic per-block partial sums. d<=20 -> fixed-max softmax:
// e = mk*exp(d-20); masked -> exactly 0.
// pro_raw PRE-SWIZZLED: row m, 16B chunk g stored at g ^ (m&7) -> linear
// global_load_lds staging + conflict-free ds_read_b128 at ch = (ks*4+lq)^ln7.
// R9 lesson: cooperative grid.sync ~90us on MI355X -- keep separate kernels.
// R13: pool = register-shuffle reduction (no LDS data path, no tail phases):
// wave reads one (channel, 8-row stripe) as 4 coalesced 1KB loads, 8x8 cells
// via shfl_xor(1)+shfl_xor(32); only a 128-float LDS merge for psum.
// ---------------------------------------------------------------------------

// K1: blocks 0..1279 = (s, gy, cq): 4 waves x 4 channels each (16 ch total),
//     register-pooled -> pro_raw f16 (swizzled) + psum[m][32] partials.
//     Blocks 1280..1284: pool sup_y shot r -> yv_ws.
__global__ __launch_bounds__(256) void pool_kernel(const float* __restrict__ sup_x,
                                                   const float* __restrict__ sup_y,
                                                   _Float16* __restrict__ pro_raw,
                                                   float* __restrict__ psum,
                                                   float* __restrict__ yv_ws) {
    const int b = blockIdx.x, t = threadIdx.x;
    if (b < 1280) {
        __shared__ float ps_l[128];
        const int s = b >> 8, rem = b & 255;
        const int gy = rem >> 4, cq = rem & 15;
        const int w = t >> 6, l = t & 63;
        const int gx = (l & 31) >> 1;
        const int mbase = s * 256 + gy * 16;

        // issue ALL 16 loads first (4 channels x 4 row-pair slabs): max MLP
        float4 v[4][4];
#pragma unroll
        for (int k = 0; k < 4; ++k) {
            const int c = cq * 16 + k * 4 + w;          // wave-adjacent channels
            const float* B = sup_x + ((size_t)(s * 256 + c) * 128 + gy * 8) * 128;
#pragma unroll
            for (int j = 0; j < 4; ++j)
                v[k][j] = *(const float4*)(B + j * 256 + l * 4);
        }

        float s1 = 0.f, s2 = 0.f;
#pragma unroll
        for (int k = 0; k < 4; ++k) {
            const int c = cq * 16 + k * 4 + w;
            float a = 0.f;
#pragma unroll
            for (int j = 0; j < 4; ++j)
                a += v[k][j].x + v[k][j].y + v[k][j].z + v[k][j].w;
            // lane l covers rows {l>>5, 2+(l>>5), 4+(l>>5), 6+(l>>5)}, cols (l&31)*4..+3
            const float p2 = a + __shfl_xor(a, 1);       // col pair merge
            const float cell = p2 + __shfl_xor(p2, 32);  // row-parity merge
            const float x = cell * (1.f / 64.f);         // pooled cell (l&31)>>1
            s1 += x; s2 += x * x;
            if (l < 32 && !(l & 1)) {
                const int m = mbase + gx;
                const int g = c >> 3;
                pro_raw[(size_t)m * 256 + ((g ^ (gx & 7)) << 3) + (c & 7)] = (_Float16)x;
            }
        }
        if (l < 32 && !(l & 1)) {
            ps_l[w * 32 + gx * 2]     = s1;
            ps_l[w * 32 + gx * 2 + 1] = s2;
        }
        __syncthreads();
        if (t < 32) {
            const int gx2 = t >> 1, which = t & 1;
            const float val = ps_l[gx2 * 2 + which] + ps_l[32 + gx2 * 2 + which]
                            + ps_l[64 + gx2 * 2 + which] + ps_l[96 + gx2 * 2 + which];
            psum[(size_t)(mbase + gx2) * 32 + cq * 2 + which] = val;
        }
    } else {
        const int r = b - 1280;
        const int gy = t >> 4, gx = t & 15;
        const float* base = sup_y + r * 16384 + gy * 1024 + gx * 8;
        float sum = 0.f;
#pragma unroll
        for (int rr = 0; rr < 8; ++rr) {
            const float4 a = *(const float4*)(base + rr * 128);
            const float4 bb = *(const float4*)(base + rr * 128 + 4);
            sum += a.x + a.y + a.z + a.w + bb.x + bb.y + bb.z + bb.w;
        }
        yv_ws[r * 256 + t] = sum * (1.f / 64.f);
    }
}

__device__ __forceinline__ void gload_lds16h(const _Float16* g, _Float16* l) {
    __builtin_amdgcn_global_load_lds((const __attribute__((address_space(1))) unsigned int*)g,
                                     (__attribute__((address_space(3))) unsigned int*)l,
                                     16, 0, 0);
}
__device__ __forceinline__ void gload_lds16f(const float* g, float* l) {
    __builtin_amdgcn_global_load_lds((const __attribute__((address_space(1))) unsigned int*)g,
                                     (__attribute__((address_space(3))) unsigned int*)l,
                                     16, 0, 0);
}

// stage one 128m x 256c f16 tile: wave w stages ITS OWN 16 rows (8KB slice)
__device__ __forceinline__ void stage_tile(const _Float16* __restrict__ pro_raw,
                                           int tile, _Float16* dst, int w, int l) {
#pragma unroll
    for (int i = 0; i < 8; ++i) {
        const int off = w * 4096 + i * 512 + l * 8;
        gload_lds16h(pro_raw + (size_t)tile * 32768 + off, dst + off);
    }
}

// compute one 128-m tile: wave owns rows w*16..w*16+15.
// epilogue: d = alpha[m]*acc ; e = mk*exp(d-20) ; S += e ; W += e*d
__device__ __forceinline__ void compute_tile(const _Float16* __restrict__ pb,
                                             const float* __restrict__ msp,
                                             const float* __restrict__ asp,
                                             const f16x8 (&bfr)[4][8],
                                             int row, int ln7, int lq,
                                             float (&Sa)[4], float (&Wa)[4]) {
    f32x4 acc[4];
#pragma unroll
    for (int p = 0; p < 4; ++p) acc[p] = (f32x4){0.f, 0.f, 0.f, 0.f};
#pragma unroll
    for (int ks = 0; ks < 8; ++ks) {
        const int ch = (ks * 4 + lq) ^ ln7;          // bank-correct swizzle
        const f16x8 a = *(const f16x8*)(pb + row * 256 + ch * 8);
#pragma unroll
        for (int p = 0; p < 4; ++p)
            acc[p] = __builtin_amdgcn_mfma_f32_16x16x32_f16(a, bfr[p][ks], acc[p], 0, 0, 0);
    }
    const f32x4 mkv = *(const f32x4*)(msp + lq * 4);
    const f32x4 av  = *(const f32x4*)(asp + lq * 4);
#pragma unroll
    for (int p = 0; p < 4; ++p) {
        float ssum = 0.f, wsum = 0.f;
#pragma unroll
        for (int r = 0; r < 4; ++r) {
            const float d = av[r] * acc[p][r];
            const float e = mkv[r] * __expf(d - 20.f);
            ssum += e; wsum += e * d;
        }
        Sa[p] += ssum; Wa[p] += wsum;
    }
}

// K2: 256 blocks x 512 thr. Prologue: stage qry -> qtf (async), meanwhile
// reduce psum -> alpha[m] + masks from yv_ws; qnorm -> qs f16; hoist B-frags.
// Main: 10 tiles of 128 m, per-wave dbuf + counted vmcnt (R10 pipeline).
__global__ __launch_bounds__(512, 2) void main_kernel(const float* __restrict__ qry,
                                                      const _Float16* __restrict__ pro_raw,
                                                      const float* __restrict__ psum,
                                                      const float* __restrict__ yv_ws,
                                                      float* __restrict__ out) {
    __shared__ __align__(16) _Float16 arena[65536];   // 128 KB
    __shared__ float ms[1280];
    __shared__ float alf[1280];
    __shared__ float scr[1024];
    __shared__ float2 stats[64];
    __shared__ int iflags[2];

    float*     qtf  = (float*)arena;        // 64 KB [c][64px] (prologue)
    _Float16*  qs   = arena + 32768;        // bytes [64K,96K) (prologue)
    _Float16*  buf0 = arena;                // bytes [0,64K)   (main)
    _Float16*  buf1 = arena + 32768;        // bytes [64K,128K)(main)
    float*     red  = (float*)arena;        // 16 KB (epilogue, overlays buf0)

    const int t = threadIdx.x;
    const int w = t >> 6, l = t & 63;
    const int ln = l & 15, lq = l >> 4;
    const int ln7 = ln & 7;
    const int px0 = blockIdx.x * 64;

    if (t < 2) iflags[t] = 0;
    __syncthreads();

    // ---- issue qry staging (latency hidden by alpha/mask compute below) ----
#pragma unroll
    for (int i = 0; i < 8; ++i) {
        const int c = i * 32 + (t >> 4);
        gload_lds16f(qry + (size_t)c * 16384 + px0 + (t & 15) * 4,
                     qtf + i * 2048 + t * 4);
    }

    // ---- alpha[m] from psum partials + mask flags (m = t, t+512, t+1024) ----
    float yv3[3];
    int f0 = 0, f1 = 0;
#pragma unroll
    for (int k = 0; k < 3; ++k) {
        const int m = t + k * 512;
        if (m < 1280) {
            float S1 = 0.f, S2 = 0.f;
            const f32x4* pp = (const f32x4*)(psum + m * 32);
#pragma unroll
            for (int u = 0; u < 8; ++u) {
                const f32x4 p = pp[u];
                S1 += p[0] + p[2]; S2 += p[1] + p[3];
            }
            alf[m] = 20.f / fmaxf(sqrtf(fmaxf(S2 - S1 * S1 * (1.f / 256.f), 0.f)), 1e-4f);
            const float y = yv_ws[m];
            yv3[k] = y;
            if (y > 0.5f) f0 = 1;
            if (y > 0.1f) f1 = 1;
        }
    }
    if (f0) atomicOr(&iflags[0], 1);
    if (f1) atomicOr(&iflags[1], 1);
    __syncthreads();   // full drain: qtf ready, flags final
    {
        const int mode = iflags[0] ? 0 : (iflags[1] ? 1 : 2);
#pragma unroll
        for (int k = 0; k < 3; ++k) {
            const int m = t + k * 512;
            if (m < 1280)
                ms[m] = (mode == 0) ? (yv3[k] > 0.5f ? 1.f : 0.f)
                      : (mode == 1) ? (yv3[k] > 0.1f ? 1.f : 0.f) : 1.f;
        }
    }

    // ---- qnorm: per-px stats then f16 convert into qs (swizzled) ----
    {
        const int p = t & 63, q = t >> 6;
        float s1 = 0.f, s2 = 0.f;
        for (int cc = 0; cc < 32; ++cc) {
            const float x = qtf[(q * 32 + cc) * 64 + p];
            s1 += x; s2 += x * x;
        }
        scr[q * 64 + p] = s1; scr[512 + q * 64 + p] = s2;
    }
    __syncthreads();
    if (t < 64) {
        float S1 = 0.f, S2 = 0.f;
        for (int q = 0; q < 8; ++q) { S1 += scr[q * 64 + t]; S2 += scr[512 + q * 64 + t]; }
        const float mu = S1 * (1.f / 256.f);
        const float nrm = sqrtf(fmaxf(S2 - 256.f * mu * mu, 0.f));
        stats[t] = make_float2(mu, 1.f / fmaxf(nrm, 1e-4f));
    }
    __syncthreads();
    {
        const int px = t & 63, e = t >> 6;
        const float2 st = stats[px];
#pragma unroll
        for (int u = 0; u < 4; ++u) {
            const int g = e * 4 + u;
            f16x8 hv;
#pragma unroll
            for (int j = 0; j < 8; ++j)
                hv[j] = (_Float16)((qtf[(g * 8 + j) * 64 + px] - st.x) * st.y);
            *(f16x8*)(qs + px * 256 + ((g ^ (px & 7)) << 3)) = hv;
        }
    }
    __syncthreads();   // qs ready; qtf dead -> buf0 region free

    stage_tile(pro_raw, 0, buf0, w, l);   // overlaps bfr hoist

    f16x8 bfr[4][8];
#pragma unroll
    for (int p = 0; p < 4; ++p) {
        const int px = p * 16 + ln;
        const int sB = px & 7;
#pragma unroll
        for (int ks = 0; ks < 8; ++ks) {
            const int g = ks * 4 + lq;
            bfr[p][ks] = *(const f16x8*)(qs + px * 256 + ((g ^ sB) << 3));
        }
    }
    __syncthreads();   // all waves done reading qs -> buf1 region free

    stage_tile(pro_raw, 1, buf1, w, l);

    const int row = w * 16 + ln;
    float Sa[4] = {0.f, 0.f, 0.f, 0.f}, Wa[4] = {0.f, 0.f, 0.f, 0.f};

#pragma unroll 1
    for (int tile = 0; tile < 10; ++tile) {
        if (tile < 8) asm volatile("s_waitcnt vmcnt(8)" ::: "memory");
        else          asm volatile("s_waitcnt vmcnt(0)" ::: "memory");
        compute_tile((tile & 1) ? buf1 : buf0,
                     ms + tile * 128 + w * 16, alf + tile * 128 + w * 16,
                     bfr, row, ln7, lq, Sa, Wa);
        if (tile < 8) {
            asm volatile("s_waitcnt lgkmcnt(0)" ::: "memory");
            __builtin_amdgcn_sched_barrier(0);
            stage_tile(pro_raw, tile + 2, (tile & 1) ? buf1 : buf0, w, l);
        }
    }

    __syncthreads();   // all waves done with buffers -> red overlay safe
#pragma unroll
    for (int p = 0; p < 4; ++p) {
        const int px = p * 16 + ln;
        const int slot = (w * 4 + lq + px) & 31;
        red[px * 32 + slot] = Sa[p];
        red[2048 + px * 32 + slot] = Wa[p];
    }
    __syncthreads();
    if (t < 64) {
        float S = 0.f, W = 0.f;
        for (int s = 0; s < 32; ++s) {
            const int slot = (s + t) & 31;
            S += red[t * 32 + slot];
            W += red[2048 + t * 32 + slot];
        }
        out[px0 + t] = W / S;
    }
}

extern "C" void kernel_launch(void* const* d_in, const int* in_sizes, int n_in,
                              void* d_out, int out_size, void* d_ws, size_t ws_size,
                              hipStream_t stream) {
    const float* qry   = (const float*)d_in[0];   // 256*16384
    const float* sup_x = (const float*)d_in[1];   // 5*256*16384
    const float* sup_y = (const float*)d_in[2];   // 5*16384
    float* out = (float*)d_out;                   // 16384

    char* ws = (char*)d_ws;
    _Float16*  pro_raw = (_Float16*)ws;           ws += 1280 * 256 * 2;   // 640 KB
    float*     psum    = (float*)ws;              ws += 1280 * 32 * 4;    // 160 KB
    float*     yv_ws   = (float*)ws;              /* 5 KB */

    pool_kernel<<<1285, 256, 0, stream>>>(sup_x, sup_y, pro_raw, psum, yv_ws);
    main_kernel<<<256, 512, 0, stream>>>(qry, pro_raw, psum, yv_ws, out);
}

// Round 14
// 41.496 us; speedup vs baseline: 1.0267x; 1.0262x over previous
//
#include <hip/hip_runtime.h>
#include <math.h>

typedef _Float16 f16x8 __attribute__((ext_vector_type(8)));
typedef float f32x4 __attribute__((ext_vector_type(4)));

// ---------------------------------------------------------------------------
// qry (256c,16384px) f32; sup_x (5,256,128,128) f32; sup_y (5,128,128) f32.
// M=1280 protos, C=256. out (16384) f32.
// pred[px] = sum_m softmax(mask? d : NEG)_m * d_m, d = 20*<q_n[px], p_n[m]>.
// Identity: sum_c q_n[c] = 0 => <q_n,(x-mu)*inv> = inv*<q_n,x> => MFMA on RAW
// pooled x (f16); epilogue d = alpha[m]*acc, alpha = 20/max(||x-mu||,1e-4).
// d<=20 -> fixed-max softmax: e = mk*exp(d-20); masked -> exactly 0.
// pro_raw & qn_h PRE-SWIZZLED: row r, 16B chunk g stored at g ^ (r&7) ->
// linear global_load_lds staging + conflict-free ds_read_b128.
// R9 lesson: cooperative grid.sync ~90us on MI355X -- separate kernels.
// R13 lesson: pool variants (1280-blk, reg-shuffle) don't beat R11's 640-blk.
// R14: qnorm rides INSIDE K1 (overlaps the 84MB sup_x stream); main drops its
// serial prologue and starts at the proto pipeline immediately.
// ---------------------------------------------------------------------------

// K1: blocks 0..639 = R11 pool (s, gy, cq32) -> pro_raw + psum[m][16].
//     blocks 640..895 = qnorm px-tile (b-640)*64 -> qn_h f16 swizzled.
//     blocks 896..900 = pool sup_y shot r -> yv_ws.
__global__ __launch_bounds__(256) void pool_kernel(const float* __restrict__ sup_x,
                                                   const float* __restrict__ qry,
                                                   const float* __restrict__ sup_y,
                                                   _Float16* __restrict__ pro_raw,
                                                   float* __restrict__ psum,
                                                   _Float16* __restrict__ qn_h,
                                                   float* __restrict__ yv_ws) {
    __shared__ float sarena[16384];         // 64 KB shared by both block types
    __shared__ float scr[512];
    const int b = blockIdx.x, t = threadIdx.x;
    if (b < 640) {
        float* hs = sarena;                 // [run 256][lane 32] h-4sums (32 KB)
        float (*xa)[33] = (float(*)[33])(sarena + 8192);   // [gx][c] pooled
        const int s = b >> 7, rem = b & 127;
        const int gy = rem >> 3, cq = rem & 7;
        const float* base = sup_x + ((size_t)(s * 256 + cq * 32) * 128 + gy * 8) * 128;
#pragma unroll 8
        for (int i = 0; i < 32; ++i) {
            const int run = i * 8 + (t >> 5);
            const float4 v = *(const float4*)(base + ((size_t)(run >> 3) * 128 + (run & 7)) * 128 + (t & 31) * 4);
            hs[i * 256 + t] = v.x + v.y + v.z + v.w;
        }
        __syncthreads();
#pragma unroll
        for (int e0 = 0; e0 < 2; ++e0) {    // entry e = (c<<4)|gx
            const int e = e0 * 256 + t;
            const int c = e >> 4, gx = e & 15;
            float sum = 0.f;
#pragma unroll
            for (int r = 0; r < 8; ++r)
                sum += hs[(c * 8 + r) * 32 + gx * 2] + hs[(c * 8 + r) * 32 + gx * 2 + 1];
            xa[gx][c] = sum * (1.f / 64.f);
        }
        __syncthreads();
        const int mbase = s * 256 + gy * 16;
        if (t < 64) {                        // 16 m x 4 chunks f16 swizzled
            const int gx = t >> 2, gi = t & 3;
            const int m = mbase + gx;
            const int g = cq * 4 + gi;
            f16x8 hv;
#pragma unroll
            for (int j = 0; j < 8; ++j) hv[j] = (_Float16)xa[gx][gi * 8 + j];
            *(f16x8*)(pro_raw + (size_t)m * 256 + ((g ^ (m & 7)) << 3)) = hv;
        } else if (t < 80) {                 // partial stats over 32 c
            const int gx = t - 64;
            float s1 = 0.f, s2 = 0.f;
#pragma unroll
            for (int c = 0; c < 32; ++c) { const float x = xa[gx][c]; s1 += x; s2 += x * x; }
            const int m = mbase + gx;
            psum[m * 16 + cq * 2]     = s1;
            psum[m * 16 + cq * 2 + 1] = s2;
        }
    } else if (b < 896) {
        // ---- qnorm tile: 64 px, overlap with pool stream ----
        float* qtf = sarena;                 // [c][64px] f32
        const int px0 = (b - 640) * 64;
#pragma unroll
        for (int i = 0; i < 16; ++i) {       // contiguous 1KB/wave-issue
            const int c = i * 16 + (t >> 4);
            __builtin_amdgcn_global_load_lds(
                (const __attribute__((address_space(1))) unsigned int*)(qry + (size_t)c * 16384 + px0 + (t & 15) * 4),
                (__attribute__((address_space(3))) unsigned int*)(qtf + c * 64 + (t & 15) * 4),
                16, 0, 0);
        }
        __syncthreads();                     // drains vmcnt -> qtf ready
        {
            const int p = t & 63, q = t >> 6;  // 4 groups x 64 c
            float s1 = 0.f, s2 = 0.f;
            for (int cc = 0; cc < 64; ++cc) {
                const float x = qtf[(q * 64 + cc) * 64 + p];
                s1 += x; s2 += x * x;
            }
            scr[q * 64 + p] = s1; scr[256 + q * 64 + p] = s2;
        }
        __syncthreads();
        __shared__ float2 stats[64];
        if (t < 64) {
            float S1 = 0.f, S2 = 0.f;
#pragma unroll
            for (int q = 0; q < 4; ++q) { S1 += scr[q * 64 + t]; S2 += scr[256 + q * 64 + t]; }
            const float mu = S1 * (1.f / 256.f);
            const float nrm = sqrtf(fmaxf(S2 - 256.f * mu * mu, 0.f));
            stats[t] = make_float2(mu, 1.f / fmaxf(nrm, 1e-4f));
        }
        __syncthreads();
        {
            const int px = t >> 2, q4 = t & 3;
            const float2 st = stats[px];
#pragma unroll
            for (int u = 0; u < 8; ++u) {
                const int g = u * 4 + q4;    // 4 lanes/px -> one 64B group
                f16x8 hv;
#pragma unroll
                for (int j = 0; j < 8; ++j)
                    hv[j] = (_Float16)((qtf[(g * 8 + j) * 64 + px] - st.x) * st.y);
                *(f16x8*)(qn_h + (size_t)(px0 + px) * 256 + ((g ^ (px & 7)) << 3)) = hv;
            }
        }
    } else {
        const int r = b - 896;
        const int gy = t >> 4, gx = t & 15;
        const float* base = sup_y + r * 16384 + gy * 1024 + gx * 8;
        float sum = 0.f;
#pragma unroll
        for (int rr = 0; rr < 8; ++rr) {
            const float4 a = *(const float4*)(base + rr * 128);
            const float4 bb = *(const float4*)(base + rr * 128 + 4);
            sum += a.x + a.y + a.z + a.w + bb.x + bb.y + bb.z + bb.w;
        }
        yv_ws[r * 256 + t] = sum * (1.f / 64.f);
    }
}

__device__ __forceinline__ void gload_lds16h(const _Float16* g, _Float16* l) {
    __builtin_amdgcn_global_load_lds((const __attribute__((address_space(1))) unsigned int*)g,
                                     (__attribute__((address_space(3))) unsigned int*)l,
                                     16, 0, 0);
}

// stage one 128m x 256c f16 tile: wave w stages ITS OWN 16 rows (8KB slice)
__device__ __forceinline__ void stage_tile(const _Float16* __restrict__ pro_raw,
                                           int tile, _Float16* dst, int w, int l) {
#pragma unroll
    for (int i = 0; i < 8; ++i) {
        const int off = w * 4096 + i * 512 + l * 8;
        gload_lds16h(pro_raw + (size_t)tile * 32768 + off, dst + off);
    }
}

// compute one 128-m tile: wave owns rows w*16..w*16+15.
__device__ __forceinline__ void compute_tile(const _Float16* __restrict__ pb,
                                             const float* __restrict__ msp,
                                             const float* __restrict__ asp,
                                             const f16x8 (&bfr)[4][8],
                                             int row, int ln7, int lq,
                                             float (&Sa)[4], float (&Wa)[4]) {
    f32x4 acc[4];
#pragma unroll
    for (int p = 0; p < 4; ++p) acc[p] = (f32x4){0.f, 0.f, 0.f, 0.f};
#pragma unroll
    for (int ks = 0; ks < 8; ++ks) {
        const int ch = (ks * 4 + lq) ^ ln7;          // bank-correct swizzle
        const f16x8 a = *(const f16x8*)(pb + row * 256 + ch * 8);
#pragma unroll
        for (int p = 0; p < 4; ++p)
            acc[p] = __builtin_amdgcn_mfma_f32_16x16x32_f16(a, bfr[p][ks], acc[p], 0, 0, 0);
    }
    const f32x4 mkv = *(const f32x4*)(msp + lq * 4);
    const f32x4 av  = *(const f32x4*)(asp + lq * 4);
#pragma unroll
    for (int p = 0; p < 4; ++p) {
        float ssum = 0.f, wsum = 0.f;
#pragma unroll
        for (int r = 0; r < 4; ++r) {
            const float d = av[r] * acc[p][r];
            const float e = mkv[r] * __expf(d - 20.f);
            ssum += e; wsum += e * d;
        }
        Sa[p] += ssum; Wa[p] += wsum;
    }
}

// K2: 256 blocks x 512 thr. NO qry prologue: masks+alpha (tiny), bfr straight
// from qn_h (L2/L3-hot), then per-wave dbuf pipeline w/ counted vmcnt.
__global__ __launch_bounds__(512, 2) void main_kernel(const _Float16* __restrict__ qn_h,
                                                      const _Float16* __restrict__ pro_raw,
                                                      const float* __restrict__ psum,
                                                      const float* __restrict__ yv_ws,
                                                      float* __restrict__ out) {
    __shared__ __align__(16) _Float16 arena[65536];   // 128 KB: buf0/buf1/red
    __shared__ float ms[1280];
    __shared__ float alf[1280];
    __shared__ int iflags[2];

    _Float16*  buf0 = arena;                // [0,64K)
    _Float16*  buf1 = arena + 32768;        // [64K,128K)
    float*     red  = (float*)arena;        // 16 KB (epilogue, overlays buf0)

    const int t = threadIdx.x;
    const int w = t >> 6, l = t & 63;
    const int ln = l & 15, lq = l >> 4;
    const int ln7 = ln & 7;
    const int px0 = blockIdx.x * 64;

    if (t < 2) iflags[t] = 0;

    // ---- bfr fragments straight from qn_h (issued first: drain on 1st wait) ----
    f16x8 bfr[4][8];
#pragma unroll
    for (int p = 0; p < 4; ++p) {
        const int px = p * 16 + ln;
        const int sB = px & 7;
#pragma unroll
        for (int ks = 0; ks < 8; ++ks) {
            const int g = ks * 4 + lq;
            bfr[p][ks] = *(const f16x8*)(qn_h + (size_t)(px0 + px) * 256 + ((g ^ sB) << 3));
        }
    }

    stage_tile(pro_raw, 0, buf0, w, l);
    stage_tile(pro_raw, 1, buf1, w, l);

    // ---- alpha[m] + mask flags (m = t, t+512, t+1024) ----
    __syncthreads();   // iflags init visible
    float yv3[3];
    int f0 = 0, f1 = 0;
#pragma unroll
    for (int k = 0; k < 3; ++k) {
        const int m = t + k * 512;
        if (m < 1280) {
            float S1 = 0.f, S2 = 0.f;
            const f32x4* pp = (const f32x4*)(psum + m * 16);
#pragma unroll
            for (int u = 0; u < 4; ++u) {
                const f32x4 p = pp[u];
                S1 += p[0] + p[2]; S2 += p[1] + p[3];
            }
            alf[m] = 20.f / fmaxf(sqrtf(fmaxf(S2 - S1 * S1 * (1.f / 256.f), 0.f)), 1e-4f);
            const float y = yv_ws[m];
            yv3[k] = y;
            if (y > 0.5f) f0 = 1;
            if (y > 0.1f) f1 = 1;
        }
    }
    if (f0) atomicOr(&iflags[0], 1);
    if (f1) atomicOr(&iflags[1], 1);
    __syncthreads();
    {
        const int mode = iflags[0] ? 0 : (iflags[1] ? 1 : 2);
#pragma unroll
        for (int k = 0; k < 3; ++k) {
            const int m = t + k * 512;
            if (m < 1280)
                ms[m] = (mode == 0) ? (yv3[k] > 0.5f ? 1.f : 0.f)
                      : (mode == 1) ? (yv3[k] > 0.1f ? 1.f : 0.f) : 1.f;
        }
    }

    const int row = w * 16 + ln;
    float Sa[4] = {0.f, 0.f, 0.f, 0.f}, Wa[4] = {0.f, 0.f, 0.f, 0.f};

#pragma unroll 1
    for (int tile = 0; tile < 10; ++tile) {
        if (tile < 8) asm volatile("s_waitcnt vmcnt(8)" ::: "memory");
        else          asm volatile("s_waitcnt vmcnt(0)" ::: "memory");
        compute_tile((tile & 1) ? buf1 : buf0,
                     ms + tile * 128 + w * 16, alf + tile * 128 + w * 16,
                     bfr, row, ln7, lq, Sa, Wa);
        if (tile < 8) {
            asm volatile("s_waitcnt lgkmcnt(0)" ::: "memory");
            __builtin_amdgcn_sched_barrier(0);
            stage_tile(pro_raw, tile + 2, (tile & 1) ? buf1 : buf0, w, l);
        }
    }

    __syncthreads();   // all waves done with buffers -> red overlay safe
#pragma unroll
    for (int p = 0; p < 4; ++p) {
        const int px = p * 16 + ln;
        const int slot = (w * 4 + lq + px) & 31;
        red[px * 32 + slot] = Sa[p];
        red[2048 + px * 32 + slot] = Wa[p];
    }
    __syncthreads();
    if (t < 64) {
        float S = 0.f, W = 0.f;
        for (int s = 0; s < 32; ++s) {
            const int slot = (s + t) & 31;
            S += red[t * 32 + slot];
            W += red[2048 + t * 32 + slot];
        }
        out[px0 + t] = W / S;
    }
}

extern "C" void kernel_launch(void* const* d_in, const int* in_sizes, int n_in,
                              void* d_out, int out_size, void* d_ws, size_t ws_size,
                              hipStream_t stream) {
    const float* qry   = (const float*)d_in[0];   // 256*16384
    const float* sup_x = (const float*)d_in[1];   // 5*256*16384
    const float* sup_y = (const float*)d_in[2];   // 5*16384
    float* out = (float*)d_out;                   // 16384

    char* ws = (char*)d_ws;
    _Float16*  pro_raw = (_Float16*)ws;           ws += 1280 * 256 * 2;   // 640 KB
    float*     psum    = (float*)ws;              ws += 1280 * 16 * 4;    // 80 KB
    float*     yv_ws   = (float*)ws;              ws += 1280 * 4;         // 5 KB
    _Float16*  qn_h    = (_Float16*)ws;           /* 8 MB */

    pool_kernel<<<901, 256, 0, stream>>>(sup_x, qry, sup_y, pro_raw, psum, qn_h, yv_ws);
    main_kernel<<<256, 512, 0, stream>>>(qn_h, pro_raw, psum, yv_ws, out);
}